// Round 1
// baseline (436.098 us; speedup 1.0000x reference)
//
#include <hip/hip_runtime.h>

#define IC 256
#define OC 512
#define NB 32
#define NP 16
#define KTOT 65536   // i*256 + c

// ---------------- Kernel A: h[b][c][p] = relu(b1[c] + sum_i W1[c][i]*x[b][i][p])
// grid: NB*NP blocks, 256 threads (thread = c)
__global__ void kA(const float* __restrict__ x, const float* __restrict__ W1,
                   const float* __restrict__ b1, float* __restrict__ h) {
    int bp = blockIdx.x;
    int b = bp >> 4, p = bp & 15;
    int c = threadIdx.x;
    __shared__ float xs[IC];
    xs[c] = x[b * 4096 + c * 16 + p];
    __syncthreads();
    float acc = b1[c];
    const float* wrow = W1 + c * IC;
    #pragma unroll 8
    for (int i = 0; i < IC; i += 4) {
        float4 w = *(const float4*)(wrow + i);
        acc += w.x * xs[i] + w.y * xs[i + 1] + w.z * xs[i + 2] + w.w * xs[i + 3];
    }
    h[b * 4096 + c * 16 + p] = fmaxf(acc, 0.f);
}

// ---------------- Kernel B: Gt[(i*256+c)*32 + b] = sum_p x[b][i][p]*h[b][c][p]
// also sx[b*256 + i] = sum_p x[b][i][p].  grid: 256 blocks (i), 256 threads (c)
__global__ void kB(const float* __restrict__ x, const float* __restrict__ h,
                   float* __restrict__ Gt, float* __restrict__ sx) {
    int i = blockIdx.x;
    int c = threadIdx.x;
    __shared__ float xsh[NB * NP];   // x[b][i][p] for this i: [32][16]
    for (int e = c; e < NB * NP; e += 256) {
        int b = e >> 4, p = e & 15;
        xsh[e] = x[b * 4096 + i * 16 + p];
    }
    __syncthreads();
    float g[NB];
    const float* hbase = h + c * 16;
    #pragma unroll 4
    for (int b = 0; b < NB; ++b) {
        float4 x0 = *(const float4*)&xsh[b * 16];
        float4 x1 = *(const float4*)&xsh[b * 16 + 4];
        float4 x2 = *(const float4*)&xsh[b * 16 + 8];
        float4 x3 = *(const float4*)&xsh[b * 16 + 12];
        const float* hp = hbase + b * 4096;
        float4 h0 = *(const float4*)(hp);
        float4 h1 = *(const float4*)(hp + 4);
        float4 h2 = *(const float4*)(hp + 8);
        float4 h3 = *(const float4*)(hp + 12);
        g[b] = x0.x * h0.x + x0.y * h0.y + x0.z * h0.z + x0.w * h0.w
             + x1.x * h1.x + x1.y * h1.y + x1.z * h1.z + x1.w * h1.w
             + x2.x * h2.x + x2.y * h2.y + x2.z * h2.z + x2.w * h2.w
             + x3.x * h3.x + x3.y * h3.y + x3.z * h3.z + x3.w * h3.w;
    }
    // thread c owns the full b-row for k = i*256+c -> contiguous 32-float store
    float* gout = Gt + (size_t)i * 8192 + (size_t)c * 32;
    #pragma unroll
    for (int j = 0; j < 8; ++j) {
        float4 v = make_float4(g[j * 4], g[j * 4 + 1], g[j * 4 + 2], g[j * 4 + 3]);
        *(float4*)(gout + j * 4) = v;
    }
    if (c < NB) {
        float s = 0.f;
        #pragma unroll
        for (int p = 0; p < 16; ++p) s += xsh[c * 16 + p];
        sx[c * IC + i] = s;
    }
}

// ---------------- Kernel C: partial[blk][b][o] = sum_{k in chunk} Gt[k][b]*W2f[o][k]
// W2f[o][k] = W2[o*65536 + k].  Full-o blocks: out-tile [32 x 512], 256 threads,
// 8x8 register tile/thread, pure k-split (W2 and Gt each read once from HBM).
#define KS 32
#define W2P 516   // padded LDS row stride (dwords): keeps b128 alignment, spreads banks
__global__ void kC(const float* __restrict__ W2, const float* __restrict__ Gt,
                   float* __restrict__ partial, int kchunk) {
    __shared__ float w2s[KS * W2P];  // [k][o]
    __shared__ float gs[KS * 32];    // [k][b]
    int tid = threadIdx.x;
    int tb = tid & 3;        // b-group: b = tb*8 + ii
    int to = tid >> 2;       // o-group: o = to*8 + jj
    int u = tid & 7;         // staging: k-float4 slot
    int orow = tid >> 3;     // staging: o row (+32 per r)
    int k0 = blockIdx.x * kchunk;

    float acc[8][8];
    #pragma unroll
    for (int ii = 0; ii < 8; ++ii)
        #pragma unroll
        for (int jj = 0; jj < 8; ++jj) acc[ii][jj] = 0.f;

    for (int ks = 0; ks < kchunk; ks += KS) {
        __syncthreads();
        // stage W2 [512 o][32 k] -> transposed w2s[k][o]
        #pragma unroll 4
        for (int r = 0; r < 16; ++r) {
            int o = orow + r * 32;
            float4 v = *(const float4*)(W2 + (size_t)o * KTOT + (k0 + ks + u * 4));
            w2s[(u * 4 + 0) * W2P + o] = v.x;
            w2s[(u * 4 + 1) * W2P + o] = v.y;
            w2s[(u * 4 + 2) * W2P + o] = v.z;
            w2s[(u * 4 + 3) * W2P + o] = v.w;
        }
        // stage Gt slab [32 k][32 b] (contiguous 4 KB)
        {
            float4 v = *(const float4*)(Gt + (size_t)(k0 + ks) * 32 + tid * 4);
            *(float4*)&gs[tid * 4] = v;
        }
        __syncthreads();
        #pragma unroll 2
        for (int k = 0; k < KS; ++k) {
            float4 g0 = *(float4*)&gs[k * 32 + tb * 8];
            float4 g1 = *(float4*)&gs[k * 32 + tb * 8 + 4];
            float4 w0 = *(float4*)&w2s[k * W2P + to * 8];
            float4 w1 = *(float4*)&w2s[k * W2P + to * 8 + 4];
            float gg[8] = {g0.x, g0.y, g0.z, g0.w, g1.x, g1.y, g1.z, g1.w};
            float ww[8] = {w0.x, w0.y, w0.z, w0.w, w1.x, w1.y, w1.z, w1.w};
            #pragma unroll
            for (int ii = 0; ii < 8; ++ii)
                #pragma unroll
                for (int jj = 0; jj < 8; ++jj)
                    acc[ii][jj] += gg[ii] * ww[jj];
        }
    }
    float* pout = partial + (size_t)blockIdx.x * 16384;
    #pragma unroll
    for (int ii = 0; ii < 8; ++ii) {
        int b = tb * 8 + ii;
        float4 v0 = make_float4(acc[ii][0], acc[ii][1], acc[ii][2], acc[ii][3]);
        float4 v1 = make_float4(acc[ii][4], acc[ii][5], acc[ii][6], acc[ii][7]);
        *(float4*)(pout + b * 512 + to * 8) = v0;
        *(float4*)(pout + b * 512 + to * 8 + 4) = v1;
    }
}

// ---------------- Kernel R: out[b][o] = sum_c partial[c][b][o] + sum_i b2[o*256+i]*sx[b][i]
__global__ void kR(const float* __restrict__ partial, const float* __restrict__ b2,
                   const float* __restrict__ sx, float* __restrict__ out, int nkc) {
    int j = blockIdx.x * 256 + threadIdx.x;  // 16384 outputs
    int b = j >> 9, o = j & 511;
    float acc = 0.f;
    for (int c = 0; c < nkc; ++c) acc += partial[(size_t)c * 16384 + j];
    const float* b2p = b2 + (size_t)o * 256;
    const float* sxp = sx + (size_t)b * 256;
    float bias = 0.f;
    #pragma unroll 8
    for (int i = 0; i < 256; i += 4) {
        float4 bv = *(const float4*)(b2p + i);
        float4 sv = *(const float4*)(sxp + i);
        bias += bv.x * sv.x + bv.y * sv.y + bv.z * sv.z + bv.w * sv.w;
    }
    out[j] = acc + bias;
}

extern "C" void kernel_launch(void* const* d_in, const int* in_sizes, int n_in,
                              void* d_out, int out_size, void* d_ws, size_t ws_size,
                              hipStream_t stream) {
    const float* x  = (const float*)d_in[0];
    const float* W1 = (const float*)d_in[1];
    const float* b1 = (const float*)d_in[2];
    const float* W2 = (const float*)d_in[3];
    const float* b2 = (const float*)d_in[4];
    // d_in[5] (Wa), d_in[6] (ba): dead code in the reference — unused.
    float* out = (float*)d_out;
    float* ws = (float*)d_ws;

    float* h       = ws;                 // 131072 floats
    float* sx      = ws + 131072;        // 8192 floats
    float* Gt      = ws + 139264;        // 2097152 floats  [k][b]
    float* partial = ws + 2236416;       // nkc * 16384 floats

    size_t avail = (ws_size / 4 > 2236416) ? ws_size / 4 - 2236416 : 0;
    int nkc = 64;
    if      (avail >= (size_t)512 * 16384) nkc = 512;
    else if (avail >= (size_t)256 * 16384) nkc = 256;
    else if (avail >= (size_t)128 * 16384) nkc = 128;
    int kchunk = KTOT / nkc;

    kA<<<NB * NP, 256, 0, stream>>>(x, W1, b1, h);
    kB<<<IC, 256, 0, stream>>>(x, h, Gt, sx);
    kC<<<nkc, 256, 0, stream>>>(W2, Gt, partial, kchunk);
    kR<<<64, 256, 0, stream>>>(partial, b2, sx, out, nkc);
}

// Round 2
// 319.287 us; speedup vs baseline: 1.3659x; 1.3659x over previous
//
#include <hip/hip_runtime.h>

#define IC 256
#define OC 512
#define NB 32
#define NP 16
#define KTOT 65536   // k = i*256 + c
#define NKC 64       // k-chunks (partial depth)
#define KCH 1024     // k per chunk
#define KS2 64       // k per LDS staging step

// ---------------- Kernel A: h[b][c][p] = relu(b1[c] + sum_i W1[c][i]*x[b][i][p])
// grid: NB*NP blocks, 256 threads (thread = c)
__global__ void kA(const float* __restrict__ x, const float* __restrict__ W1,
                   const float* __restrict__ b1, float* __restrict__ h) {
    int bp = blockIdx.x;
    int b = bp >> 4, p = bp & 15;
    int c = threadIdx.x;
    __shared__ float xs[IC];
    xs[c] = x[b * 4096 + c * 16 + p];
    __syncthreads();
    float acc = b1[c];
    const float* wrow = W1 + c * IC;
    #pragma unroll 8
    for (int i = 0; i < IC; i += 4) {
        float4 w = *(const float4*)(wrow + i);
        acc += w.x * xs[i] + w.y * xs[i + 1] + w.z * xs[i + 2] + w.w * xs[i + 3];
    }
    h[b * 4096 + c * 16 + p] = fmaxf(acc, 0.f);
}

// ---------------- Kernel B: Gt[(i*256+c)*32 + b] = sum_p x[b][i][p]*h[b][c][p]
// also sx[b*256 + i] = sum_p x[b][i][p].  grid: 256 blocks (i), 256 threads (c)
__global__ void kB(const float* __restrict__ x, const float* __restrict__ h,
                   float* __restrict__ Gt, float* __restrict__ sx) {
    int i = blockIdx.x;
    int c = threadIdx.x;
    __shared__ float xsh[NB * NP];
    for (int e = c; e < NB * NP; e += 256) {
        int b = e >> 4, p = e & 15;
        xsh[e] = x[b * 4096 + i * 16 + p];
    }
    __syncthreads();
    float g[NB];
    const float* hbase = h + c * 16;
    #pragma unroll 8
    for (int b = 0; b < NB; ++b) {
        float4 x0 = *(const float4*)&xsh[b * 16];
        float4 x1 = *(const float4*)&xsh[b * 16 + 4];
        float4 x2 = *(const float4*)&xsh[b * 16 + 8];
        float4 x3 = *(const float4*)&xsh[b * 16 + 12];
        const float* hp = hbase + b * 4096;
        float4 h0 = *(const float4*)(hp);
        float4 h1 = *(const float4*)(hp + 4);
        float4 h2 = *(const float4*)(hp + 8);
        float4 h3 = *(const float4*)(hp + 12);
        g[b] = x0.x * h0.x + x0.y * h0.y + x0.z * h0.z + x0.w * h0.w
             + x1.x * h1.x + x1.y * h1.y + x1.z * h1.z + x1.w * h1.w
             + x2.x * h2.x + x2.y * h2.y + x2.z * h2.z + x2.w * h2.w
             + x3.x * h3.x + x3.y * h3.y + x3.z * h3.z + x3.w * h3.w;
    }
    float* gout = Gt + (size_t)i * 8192 + (size_t)c * 32;
    #pragma unroll
    for (int j = 0; j < 8; ++j) {
        float4 v = make_float4(g[j * 4], g[j * 4 + 1], g[j * 4 + 2], g[j * 4 + 3]);
        *(float4*)(gout + j * 4) = v;
    }
    if (c < NB) {
        float s = 0.f;
        #pragma unroll
        for (int p = 0; p < 16; ++p) s += xsh[c * 16 + p];
        sx[c * IC + i] = s;
    }
}

// ---------------- Kernel C: partial[kc][b][o] += over k-chunk, o-tile 64
// grid: (NKC, 8) blocks, 256 threads. tile 32b x 64o, thread = 4b x 2o.
__global__ void kC(const float* __restrict__ W2, const float* __restrict__ Gt,
                   float* __restrict__ partial) {
    __shared__ float w2s[KS2 * 65];   // [o_l][k_l], stride 65 -> 2-way only
    __shared__ float gs[KS2 * 32];    // [k_l][b]
    int tid = threadIdx.x;
    int kc = blockIdx.x;              // 0..63
    int o0 = blockIdx.y * 64;         // 0..7 -> o tile
    int k0 = kc * KCH;
    int bg = tid >> 5;                // 0..7 -> b = bg*4+ii
    int ov = tid & 31;                // 0..31 -> o = o0 + ov*2 + jj
    int so = tid >> 4;                // staging o row 0..15
    int su = tid & 15;                // staging k-float4 0..15

    float acc[4][2];
    #pragma unroll
    for (int ii = 0; ii < 4; ++ii) { acc[ii][0] = 0.f; acc[ii][1] = 0.f; }

    for (int ks = 0; ks < KCH; ks += KS2) {
        __syncthreads();
        // stage W2 tile [64 o][64 k]: float4 along k, scalar scatter into stride-65
        #pragma unroll
        for (int pass = 0; pass < 4; ++pass) {
            int o_l = so + pass * 16;
            float4 v = *(const float4*)(W2 + (size_t)(o0 + o_l) * KTOT + (k0 + ks + su * 4));
            float* dst = &w2s[o_l * 65 + su * 4];
            dst[0] = v.x; dst[1] = v.y; dst[2] = v.z; dst[3] = v.w;
        }
        // stage Gt slab [64 k][32 b] (contiguous 8 KB)
        #pragma unroll
        for (int pass = 0; pass < 2; ++pass) {
            int f = tid + pass * 256;
            *(float4*)&gs[f * 4] = *(const float4*)(Gt + (size_t)(k0 + ks) * 32 + f * 4);
        }
        __syncthreads();
        #pragma unroll 4
        for (int k = 0; k < KS2; ++k) {
            float4 g = *(float4*)&gs[k * 32 + bg * 4];
            float w0 = w2s[(ov * 2) * 65 + k];
            float w1 = w2s[(ov * 2 + 1) * 65 + k];
            acc[0][0] += g.x * w0; acc[0][1] += g.x * w1;
            acc[1][0] += g.y * w0; acc[1][1] += g.y * w1;
            acc[2][0] += g.z * w0; acc[2][1] += g.z * w1;
            acc[3][0] += g.w * w0; acc[3][1] += g.w * w1;
        }
    }
    float* pout = partial + (size_t)kc * 16384 + o0 + ov * 2;
    #pragma unroll
    for (int ii = 0; ii < 4; ++ii) {
        int b = bg * 4 + ii;
        *(float2*)(pout + b * 512) = make_float2(acc[ii][0], acc[ii][1]);
    }
}

// ---------------- kBias: bias[b][o] = sum_i b2[o*256+i]*sx[b*256+i]
// grid: 64 blocks (8 o each), 256 threads (32b x 8o)
__global__ void kBias(const float* __restrict__ b2, const float* __restrict__ sx,
                      float* __restrict__ bias) {
    __shared__ float sxs[32 * 260];   // stride 260 breaks 256-stride bank aliasing
    __shared__ float b2s[8 * 260];
    int tid = threadIdx.x;
    int o0 = blockIdx.x * 8;
    #pragma unroll
    for (int p = 0; p < 32; ++p) {
        int f = tid + p * 256;
        sxs[(f >> 8) * 260 + (f & 255)] = sx[f];
    }
    #pragma unroll
    for (int p = 0; p < 8; ++p) {
        int f = tid + p * 256;
        b2s[(f >> 8) * 260 + (f & 255)] = b2[(size_t)o0 * 256 + f];
    }
    __syncthreads();
    int b = tid >> 3, ol = tid & 7;
    float acc = 0.f;
    #pragma unroll 8
    for (int i = 0; i < 256; i += 4) {
        float4 sv = *(float4*)&sxs[b * 260 + i];
        float4 wv = *(float4*)&b2s[ol * 260 + i];
        acc += sv.x * wv.x + sv.y * wv.y + sv.z * wv.z + sv.w * wv.w;
    }
    bias[b * 512 + o0 + ol] = acc;
}

// ---------------- kRed: out[j] = sum_{kc} partial[kc][j] + bias[j]
// grid: 256 blocks (64 j each), 256 threads = 4 c-groups x 64 j
__global__ void kRed(const float* __restrict__ partial, const float* __restrict__ bias,
                     float* __restrict__ out) {
    __shared__ float red[256];
    int tid = threadIdx.x;
    int q = tid >> 6, jj = tid & 63;
    int j = blockIdx.x * 64 + jj;
    float s = 0.f;
    #pragma unroll
    for (int t = 0; t < 16; ++t)
        s += partial[(size_t)(q * 16 + t) * 16384 + j];
    red[tid] = s;
    __syncthreads();
    if (tid < 64)
        out[j] = red[jj] + red[64 + jj] + red[128 + jj] + red[192 + jj] + bias[j];
}

extern "C" void kernel_launch(void* const* d_in, const int* in_sizes, int n_in,
                              void* d_out, int out_size, void* d_ws, size_t ws_size,
                              hipStream_t stream) {
    const float* x  = (const float*)d_in[0];
    const float* W1 = (const float*)d_in[1];
    const float* b1 = (const float*)d_in[2];
    const float* W2 = (const float*)d_in[3];
    const float* b2 = (const float*)d_in[4];
    // d_in[5] (Wa), d_in[6] (ba): dead code in the reference — unused.
    float* out = (float*)d_out;
    float* ws = (float*)d_ws;

    // ws layout (floats) — total 3,284,992 fl = 13.14 MB (same as the passing r1 config)
    float* h       = ws;                 // 131072; dead after kB -> reused as bias
    float* sx      = ws + 131072;        // 8192
    float* Gt      = ws + 139264;        // 2097152  [k][b]
    float* partial = ws + 2236416;       // NKC * 16384 = 1048576
    float* bias    = ws;                 // aliases h (dead by the time kBias runs)

    kA<<<NB * NP, 256, 0, stream>>>(x, W1, b1, h);
    kB<<<IC, 256, 0, stream>>>(x, h, Gt, sx);
    kBias<<<64, 256, 0, stream>>>(b2, sx, bias);
    kC<<<dim3(NKC, 8), 256, 0, stream>>>(W2, Gt, partial);
    kRed<<<256, 256, 0, stream>>>(partial, bias, out);
}